// Round 4
// baseline (186.580 us; speedup 1.0000x reference)
//
#include <hip/hip_runtime.h>

#define DDIM 2048
#define BDIM 2048
#define EPS 1e-7f
#define DPB 256                 // d per block (64 per wave)
#define B_CHUNK 8               // b-rows per block
#define B_SUB 2                 // b-rows staged per wave per stage
#define NSTAGE (B_CHUNK / B_SUB)
#define GATE_BYTES (DDIM * 64 * sizeof(float))

// ---- kernel 1: gate[d][i] = sigmoid(50 * lut[d][i]) (512 KB, L2-resident) ----
__global__ __launch_bounds__(256)
void gate_kernel(const float* __restrict__ lut, float* __restrict__ gate) {
    const int i = blockIdx.x * 256 + threadIdx.x;          // float4 index
    float4 v = reinterpret_cast<const float4*>(lut)[i];
    float4 r;
    r.x = 1.0f / (1.0f + __expf(-50.0f * v.x));
    r.y = 1.0f / (1.0f + __expf(-50.0f * v.y));
    r.z = 1.0f / (1.0f + __expf(-50.0f * v.z));
    r.w = 1.0f / (1.0f + __expf(-50.0f * v.w));
    reinterpret_cast<float4*>(gate)[i] = r;
}

// ---- kernel 2: BARRIER-FREE main kernel.
// Each wave owns 64 d and its private 3KB LDS slice; it stages its own input
// rows (coalesced float4+float2), so ds ordering within the wave replaces
// __syncthreads entirely. Waves free-run -> latency hidden by TLP+ILP.
template <bool INLINE_GATE>
__global__ __launch_bounds__(256, 4)
void lut_layer_kernel(const float* __restrict__ inputs,
                      const float* __restrict__ gsrc,   // gate (precomp) or lut
                      float* __restrict__ out) {
    __shared__ float sbuf[4][B_SUB][64 * 6];   // 12 KB/block, 3 KB/wave
    const int t    = threadIdx.x;
    const int lane = t & 63;
    const int w    = t >> 6;
    const int d0   = blockIdx.x * DPB;
    const int b0   = blockIdx.y * B_CHUNK;
    const int dme  = d0 + w * 64 + lane;       // == d0 + t

    // ---- gate row into 64 VGPRs ----
    float g[64];
    {
        const float4* gr = reinterpret_cast<const float4*>(gsrc + (size_t)dme * 64);
#pragma unroll
        for (int k = 0; k < 16; ++k) {
            float4 v = gr[k];
            if (INLINE_GATE) {
                g[4*k+0] = 1.0f / (1.0f + __expf(-50.0f * v.x));
                g[4*k+1] = 1.0f / (1.0f + __expf(-50.0f * v.y));
                g[4*k+2] = 1.0f / (1.0f + __expf(-50.0f * v.z));
                g[4*k+3] = 1.0f / (1.0f + __expf(-50.0f * v.w));
            } else {
                g[4*k+0] = v.x; g[4*k+1] = v.y; g[4*k+2] = v.z; g[4*k+3] = v.w;
            }
        }
    }

    const float* gbase = inputs + ((size_t)b0 * DDIM + d0 + w * 64) * 6;
    const size_t rstr  = (size_t)DDIM * 6;     // floats between consecutive b
    float* const lds   = &sbuf[w][0][0];

    float4 pfA[B_SUB];
    float2 pfB[B_SUB];
    auto LOAD_STAGE = [&](int s) {             // per-wave coalesced: 1536B/row
#pragma unroll
        for (int r = 0; r < B_SUB; ++r) {
            const float* src = gbase + (size_t)(s * B_SUB + r) * rstr;
            pfA[r] = *reinterpret_cast<const float4*>(src + lane * 4);
            pfB[r] = *reinterpret_cast<const float2*>(src + 256 + lane * 2);
        }
    };
    auto WRITE_STAGE = [&]() {                 // wave-private LDS, no barrier
#pragma unroll
        for (int r = 0; r < B_SUB; ++r) {
            float* dst = lds + r * (64 * 6);
            *reinterpret_cast<float4*>(dst + lane * 4)       = pfA[r];
            *reinterpret_cast<float2*>(dst + 256 + lane * 2) = pfB[r];
        }
    };

    LOAD_STAGE(0);
    WRITE_STAGE();

#pragma unroll
    for (int s = 0; s < NSTAGE; ++s) {
        if (s + 1 < NSTAGE) LOAD_STAGE(s + 1);   // globals fly during compute

#pragma unroll
        for (int r = 0; r < B_SUB; ++r) {
            const float* e = lds + r * (64 * 6) + lane * 6;
            float x0 = e[0], x1 = e[1], x2 = e[2], x3 = e[3], x4 = e[4], x5 = e[5];

            // p_q = relu(concat(1-x, x)) + eps; hi_j when MSB-first bit j is 1
            float lo0 = fmaxf(x0, 0.f) + EPS, hi0 = fmaxf(1.f - x0, 0.f) + EPS;
            float lo1 = fmaxf(x1, 0.f) + EPS, hi1 = fmaxf(1.f - x1, 0.f) + EPS;
            float lo2 = fmaxf(x2, 0.f) + EPS, hi2 = fmaxf(1.f - x2, 0.f) + EPS;
            float lo3 = fmaxf(x3, 0.f) + EPS, hi3 = fmaxf(1.f - x3, 0.f) + EPS;
            float lo4 = fmaxf(x4, 0.f) + EPS, hi4 = fmaxf(1.f - x4, 0.f) + EPS;
            float lo5 = fmaxf(x5, 0.f) + EPS, hi5 = fmaxf(1.f - x5, 0.f) + EPS;

            float m01[4] = {lo0 * lo1, lo0 * hi1, hi0 * lo1, hi0 * hi1};
            float m23[4] = {lo2 * lo3, lo2 * hi3, hi2 * lo3, hi2 * hi3};
            float m45[4] = {lo4 * lo5, lo4 * hi5, hi4 * lo5, hi4 * hi5};

            float acc = 0.f;
#pragma unroll
            for (int p = 0; p < 4; ++p) {
                float accp = 0.f;
#pragma unroll
                for (int q = 0; q < 4; ++q) {
                    const int base = p * 16 + q * 4;
                    float inner = m45[0] * g[base + 0];
                    inner = fmaf(m45[1], g[base + 1], inner);
                    inner = fmaf(m45[2], g[base + 2], inner);
                    inner = fmaf(m45[3], g[base + 3], inner);
                    accp = fmaf(m23[q], inner, accp);
                }
                acc = fmaf(m01[p], accp, acc);
            }
            __builtin_nontemporal_store(
                acc, out + (size_t)(b0 + s * B_SUB + r) * DDIM + d0 + w * 64 + lane);
        }
        if (s + 1 < NSTAGE) WRITE_STAGE();       // in-order DS => no WAR hazard
    }
}

extern "C" void kernel_launch(void* const* d_in, const int* in_sizes, int n_in,
                              void* d_out, int out_size, void* d_ws, size_t ws_size,
                              hipStream_t stream) {
    const float* inputs = (const float*)d_in[0];
    const float* lut    = (const float*)d_in[1];
    // d_in[2] (p_q_2_lut_table) is a deterministic bit-selection table whose
    // structure is folded into the product tree above.
    float* out = (float*)d_out;
    dim3 grid(DDIM / DPB, BDIM / B_CHUNK);   // (8, 256) = 2048 blocks
    dim3 block(256);

    if (ws_size >= GATE_BYTES) {
        float* gate = (float*)d_ws;
        gate_kernel<<<dim3(DDIM * 64 / 4 / 256), block, 0, stream>>>(lut, gate);
        lut_layer_kernel<false><<<grid, block, 0, stream>>>(inputs, gate, out);
    } else {
        lut_layer_kernel<true><<<grid, block, 0, stream>>>(inputs, lut, out);
    }
}